// Round 1
// baseline (1153.876 us; speedup 1.0000x reference)
//
#include <hip/hip_runtime.h>

#define T 24
#define HID 64
#define DE 32
#define G3 192  // 3*HID

// LDS layout (floats):
//  wiT  [3][DE][HID]   at 0       : wiT[g3][k][o] = W_ih[g3*64+o][k], k<32   (6144)
//  whT  [3][HID][HID]  at 6144    : whT[g3][k][o] = W_hh[g3*64+o][k]         (12288)
//  gic  [T][G3]        at 18432   : per-t constant gate preactivation        (4608)
//  hbuf [HID][256]     at 23040   : per-element hidden state                 (16384)
//  bhn  [64]           at 39424   : b_hh[128..191]
//  wlc  [64]           at 39488   : W_loc flat [2][32]
//  blc  [32]           at 39552
//  wpr  [64]           at 39584
// total 39648 floats = 158,592 bytes
#define LDS_FLOATS 39648

__device__ __forceinline__ float sigmoidf_(float v) {
    return 1.0f / (1.0f + __expf(-v));
}

extern "C" __global__ void __launch_bounds__(512, 2)
traj_gru_kernel(const float* __restrict__ x, const float* __restrict__ Wloc,
                const float* __restrict__ bloc, const float* __restrict__ tt,
                const float* __restrict__ Wih, const float* __restrict__ Whh,
                const float* __restrict__ bih, const float* __restrict__ bhh,
                const float* __restrict__ Wpred, const float* __restrict__ bpred,
                float* __restrict__ out)
{
    extern __shared__ __align__(16) float L[];
    float* wiT  = L;            // [3][DE][HID]
    float* whT  = L + 6144;     // [3][HID][HID]
    float* gic  = L + 18432;    // [T][192]
    float* hbuf = L + 23040;    // [HID][256]
    float* bhn  = L + 39424;
    float* wlc  = L + 39488;
    float* blc  = L + 39552;
    float* wpr  = L + 39584;

    const int tid = threadIdx.x;

    // ---- stage transposed weights ----
    for (int i = tid; i < G3 * HID; i += 512) {
        int g  = i >> 6;        // row in [0,192)
        int k  = i & 63;        // col in [0,64)
        int g3 = g >> 6;        // gate block
        int o  = g & 63;        // output within gate
        whT[(g3 * HID + k) * HID + o] = Whh[i];
        if (k < DE) wiT[(g3 * DE + k) * HID + o] = Wih[i];
    }
    if (tid < 64) {
        bhn[tid] = bhh[128 + tid];
        wpr[tid] = Wpred[tid];
        wlc[tid] = Wloc[tid];
    }
    if (tid < 32) blc[tid] = bloc[tid];

    // ---- gic[t][g] = b_ih[g] + (g<128 ? b_hh[g] : 0) + W_ih[g][32:]·leaky(tt[t]) ----
    for (int i = tid; i < T * G3; i += 512) {
        int t = i / G3, g = i % G3;
        float acc = bih[g] + (g < 128 ? bhh[g] : 0.0f);
        const float* ttr = tt + t * DE;
        const float* wr  = Wih + g * HID + DE;
        #pragma unroll
        for (int k = 0; k < DE; ++k) {
            float e = ttr[k];
            e = e > 0.0f ? e : 0.2f * e;
            acc = fmaf(wr[k], e, acc);
        }
        gic[i] = acc;
    }

    // ---- zero h ----
    const int e     = tid & 255;   // element within block
    const int half  = tid >> 8;    // 0 or 1 (wave-uniform)
    const int obase = half * 32;   // output slice base
    #pragma unroll
    for (int oo = 0; oo < 32; ++oo) hbuf[(obase + oo) * 256 + e] = 0.0f;
    __syncthreads();

    const long long bg = (long long)blockIdx.x * 256 + e;
    const float* xb = x + bg * (T * 2);

    float ar[32], az[32], ani[32], anh[32];

    #pragma unroll 1
    for (int t = 0; t < T; ++t) {
        const float2 xv = *(const float2*)(xb + t * 2);
        const float* gt = gic + t * G3;

        #pragma unroll
        for (int oo = 0; oo < 32; ++oo) {
            ar[oo]  = gt[obase + oo];
            az[oo]  = gt[64 + obase + oo];
            ani[oo] = gt[128 + obase + oo];
            anh[oo] = bhn[obase + oo];
        }

        // input-embedding part (K=32), ex recomputed per k (no register array)
        #pragma unroll 2
        for (int k = 0; k < DE; ++k) {
            float exk = fmaf(xv.x, wlc[k], fmaf(xv.y, wlc[DE + k], blc[k]));
            exk = exk > 0.0f ? exk : 0.2f * exk;
            const float* w0 = wiT + (0 * DE + k) * HID + obase;
            const float* w1 = wiT + (1 * DE + k) * HID + obase;
            const float* w2 = wiT + (2 * DE + k) * HID + obase;
            #pragma unroll
            for (int oo = 0; oo < 32; ++oo) {
                ar[oo]  = fmaf(w0[oo], exk, ar[oo]);
                az[oo]  = fmaf(w1[oo], exk, az[oo]);
                ani[oo] = fmaf(w2[oo], exk, ani[oo]);
            }
        }
        // recurrent part (K=64)
        #pragma unroll 2
        for (int k = 0; k < HID; ++k) {
            float hk = hbuf[k * 256 + e];
            const float* w0 = whT + (0 * HID + k) * HID + obase;
            const float* w1 = whT + (1 * HID + k) * HID + obase;
            const float* w2 = whT + (2 * HID + k) * HID + obase;
            #pragma unroll
            for (int oo = 0; oo < 32; ++oo) {
                ar[oo]  = fmaf(w0[oo], hk, ar[oo]);
                az[oo]  = fmaf(w1[oo], hk, az[oo]);
                anh[oo] = fmaf(w2[oo], hk, anh[oo]);
            }
        }

        __syncthreads();  // all reads of old h done before anyone writes new h

        #pragma unroll
        for (int oo = 0; oo < 32; ++oo) {
            float r    = sigmoidf_(ar[oo]);
            float z    = sigmoidf_(az[oo]);
            float npre = fmaf(r, anh[oo], ani[oo]);
            float en   = __expf(2.0f * npre);
            float n    = 1.0f - 2.0f / (en + 1.0f);   // tanh(npre), saturates correctly
            float hold = hbuf[(obase + oo) * 256 + e];
            hbuf[(obase + oo) * 256 + e] = fmaf(z, hold - n, n);
        }

        __syncthreads();  // new h visible before next step's reads
    }

    // ---- prediction head (half 0 only) ----
    if (half == 0) {
        float s = bpred[0];
        #pragma unroll
        for (int k = 0; k < HID; ++k) s = fmaf(hbuf[k * 256 + e], wpr[k], s);
        out[bg] = sigmoidf_(s);
    }
}

extern "C" void kernel_launch(void* const* d_in, const int* in_sizes, int n_in,
                              void* d_out, int out_size, void* d_ws, size_t ws_size,
                              hipStream_t stream) {
    const float* x     = (const float*)d_in[0];
    const float* Wloc  = (const float*)d_in[1];
    const float* bloc  = (const float*)d_in[2];
    const float* tt    = (const float*)d_in[3];
    const float* Wih   = (const float*)d_in[4];
    const float* Whh   = (const float*)d_in[5];
    const float* bih   = (const float*)d_in[6];
    const float* bhh   = (const float*)d_in[7];
    const float* Wpred = (const float*)d_in[8];
    const float* bpred = (const float*)d_in[9];
    float* out = (float*)d_out;

    const size_t lds_bytes = LDS_FLOATS * sizeof(float);  // 158,592 B
    static bool attr_set = false;
    if (!attr_set) {
        (void)hipFuncSetAttribute((const void*)traj_gru_kernel,
                                  hipFuncAttributeMaxDynamicSharedMemorySize,
                                  (int)lds_bytes);
        attr_set = true;
    }

    // 65536 elements, 256 per block (2 threads each), grid = 256 blocks (1/CU)
    hipLaunchKernelGGL(traj_gru_kernel, dim3(256), dim3(512), lds_bytes, stream,
                       x, Wloc, bloc, tt, Wih, Whh, bih, bhh, Wpred, bpred, out);
}

// Round 2
// 337.552 us; speedup vs baseline: 3.4184x; 3.4184x over previous
//
#include <hip/hip_runtime.h>

#define TN 24
#define HID 64

typedef __attribute__((ext_vector_type(8))) short bf16x8;
typedef __attribute__((ext_vector_type(4))) float f32x4;

__device__ __forceinline__ ushort bf16rn(float f) {
    uint x = __float_as_uint(f);
    uint r = x + 0x7fffu + ((x >> 16) & 1u);
    return (ushort)(r >> 16);
}
__device__ __forceinline__ float bf16tof(ushort u) {
    return __uint_as_float(((uint)u) << 16);
}
__device__ __forceinline__ float sigm(float v) { return 1.0f / (1.0f + __expf(-v)); }

extern "C" __global__ void __launch_bounds__(256, 2)
traj_gru_mfma(const float* __restrict__ x, const float* __restrict__ Wloc,
              const float* __restrict__ bloc, const float* __restrict__ tt,
              const float* __restrict__ Wih, const float* __restrict__ Whh,
              const float* __restrict__ bih, const float* __restrict__ bhh,
              const float* __restrict__ Wpred, const float* __restrict__ bpred,
              float* __restrict__ out)
{
    __shared__ float gicS[TN * 192];                 // 18432 B
    __shared__ float bhnS[64];                       //   256 B
    __shared__ float wlcS[96];                       //   384 B
    __shared__ __align__(16) ushort Hhi[4][16][72];  //  9216 B
    __shared__ __align__(16) ushort Hlo[4][16][72];  //  9216 B
    __shared__ __align__(16) ushort WnF[4][64][8];   //  4096 B

    const int tid  = threadIdx.x;
    const int lane = tid & 63;
    const int wid  = tid >> 6;       // wave 0..3
    const int er   = lane & 15;      // A-row / B-col / D-col index
    const int cp   = lane >> 4;      // k-block / D-row-block

    // ---------- setup: gic[t][g] = b_ih[g] + (g<128? b_hh[g]:0) + Wih[g][32:]·leaky(tt[t]) ----------
    for (int i = tid; i < TN * 192; i += 256) {
        int t = i / 192, g = i % 192;
        float acc = bih[g] + (g < 128 ? bhh[g] : 0.0f);
        const float* ttr = tt + t * 32;
        const float* wr  = Wih + g * 64 + 32;
        #pragma unroll
        for (int k = 0; k < 32; ++k) {
            float e = ttr[k];
            e = e > 0.0f ? e : 0.2f * e;
            acc = fmaf(wr[k], e, acc);
        }
        gicS[i] = acc;
    }
    if (tid < 64) bhnS[tid] = bhh[128 + tid];
    if (tid < 96) wlcS[tid] = (tid < 64) ? Wloc[tid] : bloc[tid - 64];

    // ---------- setup: weight fragments ----------
    // A-frag layout assumption (mfma_f32_16x16x32_bf16): lane holds A[row=lane&15][k=8*(lane>>4)+j], j=0..7
    bf16x8 wihRZ[2][4];     // gates r,z input-part (K=32)
    bf16x8 whhF[3][4][2];   // gates r,z,n recurrent (K=64 -> 2 frags)
    {
        #pragma unroll
        for (int g = 0; g < 2; ++g)
            #pragma unroll
            for (int a = 0; a < 4; ++a) {
                int o = g * 64 + a * 16 + er;
                const float* p = Wih + (size_t)o * 64 + 8 * cp;
                union { ushort u[8]; bf16x8 v; } fr;
                #pragma unroll
                for (int j = 0; j < 8; ++j) fr.u[j] = bf16rn(p[j]);
                wihRZ[g][a] = fr.v;
            }
        #pragma unroll
        for (int g = 0; g < 3; ++g)
            #pragma unroll
            for (int a = 0; a < 4; ++a)
                #pragma unroll
                for (int f = 0; f < 2; ++f) {
                    int o = g * 64 + a * 16 + er;
                    const float* p = Whh + (size_t)o * 64 + 32 * f + 8 * cp;
                    union { ushort u[8]; bf16x8 v; } fr;
                    #pragma unroll
                    for (int j = 0; j < 8; ++j) fr.u[j] = bf16rn(p[j]);
                    whhF[g][a][f] = fr.v;
                }
        // n-gate input-part frags -> LDS (saves 16 VGPR): WnF[a][lane]
        {
            int a = wid;
            int o = 128 + a * 16 + er;
            const float* p = Wih + (size_t)o * 64 + 8 * cp;
            union { ushort u[8]; bf16x8 v; } fr;
            #pragma unroll
            for (int j = 0; j < 8; ++j) fr.u[j] = bf16rn(p[j]);
            *(bf16x8*)&WnF[a][lane][0] = fr.v;
        }
    }
    __syncthreads();   // the only barrier

    // ---------- main loop: wave handles 16 elements, no cross-wave deps ----------
    const long long eg = (long long)(blockIdx.x * 4 + wid) * 16 + er;  // this lane's element
    const float* xr = x + eg * (TN * 2);

    float hold[4][4];   // f32 master copy of h for (elem=er, o = 16a + 4cp + q)
    #pragma unroll
    for (int a = 0; a < 4; ++a)
        #pragma unroll
        for (int q = 0; q < 4; ++q) hold[a][q] = 0.0f;

    #pragma unroll 1
    for (int t = 0; t < TN; ++t) {
        const float2 xv = *(const float2*)(xr + t * 2);

        // ex B-frag: ex[k = 8cp+j][elem = er]
        f32x4 w1a = *(const f32x4*)&wlcS[8 * cp];
        f32x4 w1b = *(const f32x4*)&wlcS[8 * cp + 4];
        f32x4 w2a = *(const f32x4*)&wlcS[32 + 8 * cp];
        f32x4 w2b = *(const f32x4*)&wlcS[32 + 8 * cp + 4];
        f32x4 bla = *(const f32x4*)&wlcS[64 + 8 * cp];
        f32x4 blb = *(const f32x4*)&wlcS[64 + 8 * cp + 4];
        union { ushort u[8]; bf16x8 v; } exf;
        #pragma unroll
        for (int j = 0; j < 4; ++j) {
            float v = fmaf(xv.x, w1a[j], fmaf(xv.y, w2a[j], bla[j]));
            v = v > 0.0f ? v : 0.2f * v;
            exf.u[j] = bf16rn(v);
        }
        #pragma unroll
        for (int j = 0; j < 4; ++j) {
            float v = fmaf(xv.x, w1b[j], fmaf(xv.y, w2b[j], blb[j]));
            v = v > 0.0f ? v : 0.2f * v;
            exf.u[4 + j] = bf16rn(v);
        }

        // accumulator init from gic / bhn (f32)
        const float* gt = gicS + t * 192;
        f32x4 accR[4], accZ[4], accNi[4], accNh[4];
        #pragma unroll
        for (int a = 0; a < 4; ++a) {
            accR[a]  = *(const f32x4*)(gt + a * 16 + 4 * cp);
            accZ[a]  = *(const f32x4*)(gt + 64 + a * 16 + 4 * cp);
            accNi[a] = *(const f32x4*)(gt + 128 + a * 16 + 4 * cp);
            accNh[a] = *(const f32x4*)(bhnS + a * 16 + 4 * cp);
        }

        // input-part MFMAs (K=32): D[o×elem] += Wih·exT
        #pragma unroll
        for (int a = 0; a < 4; ++a) {
            accR[a] = __builtin_amdgcn_mfma_f32_16x16x32_bf16(wihRZ[0][a], exf.v, accR[a], 0, 0, 0);
            accZ[a] = __builtin_amdgcn_mfma_f32_16x16x32_bf16(wihRZ[1][a], exf.v, accZ[a], 0, 0, 0);
            bf16x8 wn = *(const bf16x8*)&WnF[a][lane][0];
            accNi[a] = __builtin_amdgcn_mfma_f32_16x16x32_bf16(wn, exf.v, accNi[a], 0, 0, 0);
        }

        // recurrent MFMAs (K=64, h = hi + lo split bf16)
        if (t > 0) {
            bf16x8 hhi0 = *(const bf16x8*)&Hhi[wid][er][8 * cp];
            bf16x8 hhi1 = *(const bf16x8*)&Hhi[wid][er][32 + 8 * cp];
            bf16x8 hlo0 = *(const bf16x8*)&Hlo[wid][er][8 * cp];
            bf16x8 hlo1 = *(const bf16x8*)&Hlo[wid][er][32 + 8 * cp];
            #pragma unroll
            for (int a = 0; a < 4; ++a) {
                accR[a]  = __builtin_amdgcn_mfma_f32_16x16x32_bf16(whhF[0][a][0], hhi0, accR[a], 0, 0, 0);
                accR[a]  = __builtin_amdgcn_mfma_f32_16x16x32_bf16(whhF[0][a][1], hhi1, accR[a], 0, 0, 0);
                accR[a]  = __builtin_amdgcn_mfma_f32_16x16x32_bf16(whhF[0][a][0], hlo0, accR[a], 0, 0, 0);
                accR[a]  = __builtin_amdgcn_mfma_f32_16x16x32_bf16(whhF[0][a][1], hlo1, accR[a], 0, 0, 0);
                accZ[a]  = __builtin_amdgcn_mfma_f32_16x16x32_bf16(whhF[1][a][0], hhi0, accZ[a], 0, 0, 0);
                accZ[a]  = __builtin_amdgcn_mfma_f32_16x16x32_bf16(whhF[1][a][1], hhi1, accZ[a], 0, 0, 0);
                accZ[a]  = __builtin_amdgcn_mfma_f32_16x16x32_bf16(whhF[1][a][0], hlo0, accZ[a], 0, 0, 0);
                accZ[a]  = __builtin_amdgcn_mfma_f32_16x16x32_bf16(whhF[1][a][1], hlo1, accZ[a], 0, 0, 0);
                accNh[a] = __builtin_amdgcn_mfma_f32_16x16x32_bf16(whhF[2][a][0], hhi0, accNh[a], 0, 0, 0);
                accNh[a] = __builtin_amdgcn_mfma_f32_16x16x32_bf16(whhF[2][a][1], hhi1, accNh[a], 0, 0, 0);
                accNh[a] = __builtin_amdgcn_mfma_f32_16x16x32_bf16(whhF[2][a][0], hlo0, accNh[a], 0, 0, 0);
                accNh[a] = __builtin_amdgcn_mfma_f32_16x16x32_bf16(whhF[2][a][1], hlo1, accNh[a], 0, 0, 0);
            }
        }

        // epilogue: gates + h update (f32), pack hi/lo bf16 and store to per-wave LDS
        #pragma unroll
        for (int a = 0; a < 4; ++a) {
            ushort hiu[4], lou[4];
            #pragma unroll
            for (int q = 0; q < 4; ++q) {
                float r  = sigm(accR[a][q]);
                float z  = sigm(accZ[a][q]);
                float np = fmaf(r, accNh[a][q], accNi[a][q]);
                float e2 = __expf(2.0f * np);
                float n  = 1.0f - 2.0f / (e2 + 1.0f);      // tanh
                float h  = n + z * (hold[a][q] - n);
                hold[a][q] = h;
                ushort hi = bf16rn(h);
                hiu[q] = hi;
                lou[q] = bf16rn(h - bf16tof(hi));
            }
            uint2 whi, wlo;
            whi.x = (uint)hiu[0] | ((uint)hiu[1] << 16);
            whi.y = (uint)hiu[2] | ((uint)hiu[3] << 16);
            wlo.x = (uint)lou[0] | ((uint)lou[1] << 16);
            wlo.y = (uint)lou[2] | ((uint)lou[3] << 16);
            *(uint2*)&Hhi[wid][er][16 * a + 4 * cp] = whi;
            *(uint2*)&Hlo[wid][er][16 * a + 4 * cp] = wlo;
        }
    }

    // ---------- prediction head ----------
    float part = 0.0f;
    #pragma unroll
    for (int a = 0; a < 4; ++a) {
        f32x4 wp = *(const f32x4*)(Wpred + 16 * a + 4 * cp);
        #pragma unroll
        for (int q = 0; q < 4; ++q) part = fmaf(hold[a][q], wp[q], part);
    }
    part += __shfl_xor(part, 16);
    part += __shfl_xor(part, 32);
    if (cp == 0) out[eg] = sigm(part + bpred[0]);
}

extern "C" void kernel_launch(void* const* d_in, const int* in_sizes, int n_in,
                              void* d_out, int out_size, void* d_ws, size_t ws_size,
                              hipStream_t stream) {
    const float* x     = (const float*)d_in[0];
    const float* Wloc  = (const float*)d_in[1];
    const float* bloc  = (const float*)d_in[2];
    const float* tt    = (const float*)d_in[3];
    const float* Wih   = (const float*)d_in[4];
    const float* Whh   = (const float*)d_in[5];
    const float* bih   = (const float*)d_in[6];
    const float* bhh   = (const float*)d_in[7];
    const float* Wpred = (const float*)d_in[8];
    const float* bpred = (const float*)d_in[9];
    float* out = (float*)d_out;

    // 65536 elements / (4 waves * 16 elem) = 1024 blocks of 256 threads
    hipLaunchKernelGGL(traj_gru_mfma, dim3(1024), dim3(256), 0, stream,
                       x, Wloc, bloc, tt, Wih, Whh, bih, bhh, Wpred, bpred, out);
}